// Round 1
// baseline (3419.176 us; speedup 1.0000x reference)
//
#include <hip/hip_runtime.h>

#define N_NODES 50000
#define N_EDGES 640000
#define D 128

// ---------------------------------------------------------------------------
// SpMM scatter: Y[r,:] += v * x[c,:]  for each edge (r,c,v).
// 32 threads per edge, float4 per thread -> coalesced 512B gather + 4 atomics.
// Grid is exact: N_EDGES*32/256 blocks, no bounds check needed.
// ---------------------------------------------------------------------------
__global__ __launch_bounds__(256) void spmm_scatter(
    const float* __restrict__ x,
    const int*   __restrict__ rows,
    const int*   __restrict__ cols,
    const float* __restrict__ vals,
    float*       __restrict__ Y)
{
    int gid = blockIdx.x * 256 + threadIdx.x;
    int e = gid >> 5;        // edge index
    int q = gid & 31;        // float4 slot within the 128-col row
    int r = rows[e];
    int c = cols[e];
    float v = vals[e];
    float4 m = ((const float4*)(x + (size_t)c * D))[q];
    float* yo = Y + (size_t)r * D + q * 4;
    atomicAdd(yo + 0, v * m.x);
    atomicAdd(yo + 1, v * m.y);
    atomicAdd(yo + 2, v * m.z);
    atomicAdd(yo + 3, v * m.w);
}

// ---------------------------------------------------------------------------
// GEMM: out[n,:] (op)= Y[n,:] @ W[:,:]   (M=50000, K=128, N=128, fp32 VALU)
// Block: 64 nodes x 128 cols, 256 threads, each thread 8 nodes x 4 cols.
// Y tile staged transposed in LDS (stride 68: 16B-aligned b128 reads,
// write banks differ by 16 -> only free 2-way conflicts).
// mode: 0 = store, 1 = accumulate, 2 = accumulate + bias + relu (last pass)
// ---------------------------------------------------------------------------
__global__ __launch_bounds__(256) void gemm_acc(
    const float* __restrict__ Y,
    const float* __restrict__ W,     // [128][128], row = k, col = out
    const float* __restrict__ bias,
    float*       __restrict__ out,
    int mode)
{
    __shared__ float ys[D * 68];     // ys[k*68 + n_local], 34.8 KB
    const int tid = threadIdx.x;
    const int nbase = blockIdx.x * 64;

    // ---- stage Y[nbase:nbase+64, 0:128] transposed into LDS ----
    {
        int sn = tid >> 2;           // node_local 0..63
        int sk = (tid & 3) * 4;      // k chunk base 0,4,8,12
        int gn = nbase + sn;
        const float4* src = (const float4*)(Y + (size_t)gn * D);
        #pragma unroll
        for (int i = 0; i < 8; ++i) {
            int k = sk + i * 16;
            float4 t4 = make_float4(0.f, 0.f, 0.f, 0.f);
            if (gn < N_NODES) t4 = src[k >> 2];
            ys[(k + 0) * 68 + sn] = t4.x;
            ys[(k + 1) * 68 + sn] = t4.y;
            ys[(k + 2) * 68 + sn] = t4.z;
            ys[(k + 3) * 68 + sn] = t4.w;
        }
    }
    __syncthreads();

    const int ng = (tid >> 5) * 8;   // local node group base (0..56)
    const int c0 = (tid & 31) * 4;   // output col base

    float4 acc[8];
    #pragma unroll
    for (int i = 0; i < 8; ++i) acc[i] = make_float4(0.f, 0.f, 0.f, 0.f);

    const float4* wp = (const float4*)(W + c0);
    #pragma unroll 4
    for (int k = 0; k < D; ++k) {
        float4 w  = wp[k * (D / 4)];
        float4 y0 = *(const float4*)&ys[k * 68 + ng];
        float4 y1 = *(const float4*)&ys[k * 68 + ng + 4];
        float yv[8] = {y0.x, y0.y, y0.z, y0.w, y1.x, y1.y, y1.z, y1.w};
        #pragma unroll
        for (int i = 0; i < 8; ++i) {
            acc[i].x += yv[i] * w.x;
            acc[i].y += yv[i] * w.y;
            acc[i].z += yv[i] * w.z;
            acc[i].w += yv[i] * w.w;
        }
    }

    // ---- epilogue ----
    float4 b = *(const float4*)(bias + c0);
    #pragma unroll
    for (int i = 0; i < 8; ++i) {
        int n = nbase + ng + i;
        if (n >= N_NODES) continue;
        float4* op = (float4*)(out + (size_t)n * D + c0);
        float4 r = acc[i];
        if (mode > 0) {
            float4 p = *op;
            r.x += p.x; r.y += p.y; r.z += p.z; r.w += p.w;
        }
        if (mode == 2) {
            r.x = fmaxf(r.x + b.x, 0.f);
            r.y = fmaxf(r.y + b.y, 0.f);
            r.z = fmaxf(r.z + b.z, 0.f);
            r.w = fmaxf(r.w + b.w, 0.f);
        }
        *op = r;
    }
}

extern "C" void kernel_launch(void* const* d_in, const int* in_sizes, int n_in,
                              void* d_out, int out_size, void* d_ws, size_t ws_size,
                              hipStream_t stream)
{
    const float* x         = (const float*)d_in[0];
    const int*   edge_rows = (const int*)  d_in[1];
    const int*   edge_cols = (const int*)  d_in[2];
    const float* edge_vals = (const float*)d_in[3];
    const float* weights   = (const float*)d_in[4];
    const float* bias      = (const float*)d_in[5];
    float* out = (float*)d_out;
    float* Y   = (float*)d_ws;   // one [N_NODES, 128] fp32 buffer, 25.6 MB

    const size_t ybytes = (size_t)N_NODES * D * sizeof(float);
    const int spmm_blocks = N_EDGES * 32 / 256;          // 80000
    const int gemm_blocks = (N_NODES + 63) / 64;         // 782

    for (int s = 0; s < 3; ++s) {
        hipMemsetAsync(Y, 0, ybytes, stream);
        spmm_scatter<<<spmm_blocks, 256, 0, stream>>>(
            x,
            edge_rows + (size_t)s * N_EDGES,
            edge_cols + (size_t)s * N_EDGES,
            edge_vals + (size_t)s * N_EDGES,
            Y);
        int mode = (s == 0) ? 0 : ((s == 2) ? 2 : 1);
        gemm_acc<<<gemm_blocks, 256, 0, stream>>>(
            Y, weights + (size_t)s * D * D, bias, out, mode);
    }
}

// Round 2
// 538.216 us; speedup vs baseline: 6.3528x; 6.3528x over previous
//
#include <hip/hip_runtime.h>

#define N_NODES 50000
#define N_EDGES 640000
#define N_SUP   3
#define D       128
#define NTOT    (N_SUP * N_NODES)        // 150000 rows total
#define E_TOT   (N_SUP * N_EDGES)        // 1920000 edges total
#define NB_SCAN ((NTOT + 255) / 256)     // 587 scan blocks

// ---------------------------------------------------------------------------
// Phase 1: per-(support,row) edge histogram. 1.92M atomics on a 600 KB
// L2-resident counter array (avg 12.8 hits/counter -> low contention).
// Grid = E_TOT/256 = 7500 exactly; 2500 blocks per support.
// ---------------------------------------------------------------------------
__global__ __launch_bounds__(256) void edge_histogram(
    const int* __restrict__ rows, int* __restrict__ counts)
{
    int i = blockIdx.x * 256 + threadIdx.x;
    int s = blockIdx.x / 2500;               // wave-uniform support index
    atomicAdd(&counts[s * N_NODES + rows[i]], 1);
}

// ---------------------------------------------------------------------------
// Phase 2: exclusive scan of 150k counts (3 tiny kernels).
// ---------------------------------------------------------------------------
__global__ __launch_bounds__(256) void scan_partials(
    const int* __restrict__ counts, int* __restrict__ bsums)
{
    __shared__ int sm[256];
    int tid = threadIdx.x;
    int i = blockIdx.x * 256 + tid;
    sm[tid] = (i < NTOT) ? counts[i] : 0;
    __syncthreads();
    for (int off = 128; off > 0; off >>= 1) {
        if (tid < off) sm[tid] += sm[tid + off];
        __syncthreads();
    }
    if (tid == 0) bsums[blockIdx.x] = sm[0];
}

__global__ __launch_bounds__(1024) void scan_bsums(int* __restrict__ bsums)
{
    __shared__ int sm[1024];
    int tid = threadIdx.x;
    int v = (tid < NB_SCAN) ? bsums[tid] : 0;
    sm[tid] = v;
    __syncthreads();
    for (int off = 1; off < 1024; off <<= 1) {     // Hillis-Steele inclusive
        int t = (tid >= off) ? sm[tid - off] : 0;
        __syncthreads();
        sm[tid] += t;
        __syncthreads();
    }
    if (tid < NB_SCAN) bsums[tid] = sm[tid] - v;   // -> exclusive
}

__global__ __launch_bounds__(256) void scan_final(
    const int* __restrict__ counts, const int* __restrict__ bsums,
    int* __restrict__ row_ptr, int* __restrict__ wptr)
{
    __shared__ int sm[256];
    int tid = threadIdx.x;
    int i = blockIdx.x * 256 + tid;
    int v = (i < NTOT) ? counts[i] : 0;
    sm[tid] = v;
    __syncthreads();
    for (int off = 1; off < 256; off <<= 1) {
        int t = (tid >= off) ? sm[tid - off] : 0;
        __syncthreads();
        sm[tid] += t;
        __syncthreads();
    }
    int excl = sm[tid] - v + bsums[blockIdx.x];
    if (i < NTOT) { row_ptr[i] = excl; wptr[i] = excl; }
}

// ---------------------------------------------------------------------------
// Phase 3: scatter edges into row-grouped order. wptr starts at row_ptr and
// ends at row end -> gather uses [row_ptr, wptr) afterwards.
// ---------------------------------------------------------------------------
__global__ __launch_bounds__(256) void edge_scatter(
    const int* __restrict__ rows, const int* __restrict__ cols,
    const float* __restrict__ vals, int* __restrict__ wptr,
    float2* __restrict__ sorted)
{
    int i = blockIdx.x * 256 + threadIdx.x;
    int s = blockIdx.x / 2500;
    int pos = atomicAdd(&wptr[s * N_NODES + rows[i]], 1);
    sorted[pos] = make_float2(__int_as_float(cols[i]), vals[i]);
}

// ---------------------------------------------------------------------------
// Phase 4: gather-SpMM. One wave per (support,row): lanes hold 2 output
// floats; per edge, (col,val) broadcast by shfl, x[col] read as a fully
// coalesced 512B wave load. Row written once -> zero atomics, and
// zero-degree rows write zeros (no Y memset needed).
// ---------------------------------------------------------------------------
__global__ __launch_bounds__(256) void spmm_gather(
    const float* __restrict__ x, const int* __restrict__ row_ptr,
    const int* __restrict__ row_end, const float2* __restrict__ sorted,
    float* __restrict__ Y, int nrows)
{
    int wid  = (blockIdx.x * 256 + threadIdx.x) >> 6;
    int lane = threadIdx.x & 63;
    if (wid >= nrows) return;
    int start = row_ptr[wid];
    int end   = row_end[wid];
    float acc0 = 0.f, acc1 = 0.f;
    for (int j = start; j < end; j += 64) {
        int m = end - j; if (m > 64) m = 64;
        float2 ev = make_float2(0.f, 0.f);
        if (lane < m) ev = sorted[j + lane];
        for (int t = 0; t < m; ++t) {
            int   col = __float_as_int(__shfl(ev.x, t));
            float v   = __shfl(ev.y, t);
            float2 xv = ((const float2*)(x + (size_t)col * D))[lane];
            acc0 += v * xv.x;
            acc1 += v * xv.y;
        }
    }
    ((float2*)(Y + (size_t)wid * D))[lane] = make_float2(acc0, acc1);
}

// ---------------------------------------------------------------------------
// Phase 5: out = relu(bias + sum_s Y_s @ W_s). Block: 64 nodes x 128 cols,
// thread: 8x4. Y tile staged transposed in LDS (stride 68 -> 16B-aligned
// reads, free 2-way bank aliasing only). nsup=3 accumulates all supports in
// registers -> no out RMW round-trips.
// ---------------------------------------------------------------------------
__global__ __launch_bounds__(256) void gemm_multi(
    const float* __restrict__ Y, size_t ystride,
    const float* __restrict__ W,          // [nsup][D][D], row=k col=o
    const float* __restrict__ bias,
    float* __restrict__ out,
    int nsup, int do_read, int do_final)
{
    __shared__ float ys[D * 68];
    const int tid   = threadIdx.x;
    const int nbase = blockIdx.x * 64;
    const int ng    = (tid >> 5) * 8;     // local node group base
    const int c0    = (tid & 31) * 4;     // output col base

    float4 acc[8];
    #pragma unroll
    for (int i = 0; i < 8; ++i) acc[i] = make_float4(0.f, 0.f, 0.f, 0.f);

    for (int s = 0; s < nsup; ++s) {
        if (s) __syncthreads();           // previous tile fully consumed
        {
            int sn = tid >> 2;            // node_local 0..63
            int sk = (tid & 3) * 4;       // k chunk base
            int gn = nbase + sn;
            const float4* src = (const float4*)(Y + s * ystride + (size_t)gn * D);
            #pragma unroll
            for (int i = 0; i < 8; ++i) {
                int k = sk + i * 16;
                float4 t4 = make_float4(0.f, 0.f, 0.f, 0.f);
                if (gn < N_NODES) t4 = src[k >> 2];
                ys[(k + 0) * 68 + sn] = t4.x;
                ys[(k + 1) * 68 + sn] = t4.y;
                ys[(k + 2) * 68 + sn] = t4.z;
                ys[(k + 3) * 68 + sn] = t4.w;
            }
        }
        __syncthreads();

        const float4* wp = (const float4*)(W + (size_t)s * D * D + c0);
        #pragma unroll 4
        for (int k = 0; k < D; ++k) {
            float4 w  = wp[k * (D / 4)];
            float4 y0 = *(const float4*)&ys[k * 68 + ng];
            float4 y1 = *(const float4*)&ys[k * 68 + ng + 4];
            float yv[8] = {y0.x, y0.y, y0.z, y0.w, y1.x, y1.y, y1.z, y1.w};
            #pragma unroll
            for (int i = 0; i < 8; ++i) {
                acc[i].x += yv[i] * w.x;
                acc[i].y += yv[i] * w.y;
                acc[i].z += yv[i] * w.z;
                acc[i].w += yv[i] * w.w;
            }
        }
    }

    float4 b = *(const float4*)(bias + c0);
    #pragma unroll
    for (int i = 0; i < 8; ++i) {
        int n = nbase + ng + i;
        if (n >= N_NODES) continue;
        float4* op = (float4*)(out + (size_t)n * D + c0);
        float4 r = acc[i];
        if (do_read) {
            float4 p = *op;
            r.x += p.x; r.y += p.y; r.z += p.z; r.w += p.w;
        }
        if (do_final) {
            r.x = fmaxf(r.x + b.x, 0.f);
            r.y = fmaxf(r.y + b.y, 0.f);
            r.z = fmaxf(r.z + b.z, 0.f);
            r.w = fmaxf(r.w + b.w, 0.f);
        }
        *op = r;
    }
}

extern "C" void kernel_launch(void* const* d_in, const int* in_sizes, int n_in,
                              void* d_out, int out_size, void* d_ws, size_t ws_size,
                              hipStream_t stream)
{
    const float* x         = (const float*)d_in[0];
    const int*   edge_rows = (const int*)  d_in[1];
    const int*   edge_cols = (const int*)  d_in[2];
    const float* edge_vals = (const float*)d_in[3];
    const float* weights   = (const float*)d_in[4];
    const float* bias      = (const float*)d_in[5];
    float* out = (float*)d_out;

    // workspace layout (256B aligned)
    char* ws = (char*)d_ws;
    size_t off = 0;
    auto alloc = [&](size_t bytes) -> char* {
        char* p = ws + off;
        off += (bytes + 255) & ~(size_t)255;
        return p;
    };
    int*    counts  = (int*)   alloc((size_t)NTOT * 4);
    int*    row_ptr = (int*)   alloc((size_t)NTOT * 4);
    int*    wptr    = (int*)   alloc((size_t)NTOT * 4);
    int*    bsums   = (int*)   alloc(1024 * 4);
    float2* sorted  = (float2*)alloc((size_t)E_TOT * 8);
    float*  Y       = (float*) (ws + off);
    size_t need_fused = off + (size_t)NTOT * D * 4;     // Y3: 76.8 MB
    bool fused = (ws_size >= need_fused);

    // ---- build CSR (all 3 supports at once) ----
    hipMemsetAsync(counts, 0, (size_t)NTOT * 4, stream);
    edge_histogram<<<E_TOT / 256, 256, 0, stream>>>(edge_rows, counts);
    scan_partials <<<NB_SCAN, 256, 0, stream>>>(counts, bsums);
    scan_bsums    <<<1, 1024, 0, stream>>>(bsums);
    scan_final    <<<NB_SCAN, 256, 0, stream>>>(counts, bsums, row_ptr, wptr);
    edge_scatter  <<<E_TOT / 256, 256, 0, stream>>>(edge_rows, edge_cols,
                                                    edge_vals, wptr, sorted);

    if (fused) {
        // one gather over all 150k rows, one GEMM accumulating 3 supports
        spmm_gather<<<NTOT / 4, 256, 0, stream>>>(x, row_ptr, wptr, sorted, Y, NTOT);
        gemm_multi<<<(N_NODES + 63) / 64, 256, 0, stream>>>(
            Y, (size_t)N_NODES * D, weights, bias, out, N_SUP, 0, 1);
    } else {
        // per-support: Y reused (25.6 MB), out accumulated across passes
        for (int s = 0; s < N_SUP; ++s) {
            spmm_gather<<<N_NODES / 4, 256, 0, stream>>>(
                x, row_ptr + (size_t)s * N_NODES, wptr + (size_t)s * N_NODES,
                sorted, Y, N_NODES);
            gemm_multi<<<(N_NODES + 63) / 64, 256, 0, stream>>>(
                Y, 0, weights + (size_t)s * D * D, bias, out,
                1, s > 0 ? 1 : 0, s == 2 ? 1 : 0);
        }
    }
}

// Round 3
// 457.369 us; speedup vs baseline: 7.4757x; 1.1768x over previous
//
#include <hip/hip_runtime.h>

#define N_NODES 50000
#define N_EDGES 640000
#define N_SUP   3
#define D       128
#define NTOT    (N_SUP * N_NODES)        // 150000 rows total
#define E_TOT   (N_SUP * N_EDGES)        // 1920000 edges total
#define NB_SCAN ((NTOT + 255) / 256)     // 586 scan blocks
#define NWAVES  (N_NODES / 16)           // 3125 gemm waves

typedef __attribute__((ext_vector_type(4))) float f32x4;
typedef __attribute__((ext_vector_type(8))) short s16x8;

__device__ __forceinline__ unsigned short f2bf(float f) {   // RNE
    unsigned int u = __float_as_uint(f);
    u += 0x7FFFu + ((u >> 16) & 1u);
    return (unsigned short)(u >> 16);
}

// ---------------------------------------------------------------------------
// x -> bf16 (halves gather traffic). 6.4M elems as float4 -> ushort4.
// ---------------------------------------------------------------------------
__global__ __launch_bounds__(256) void x_to_bf16(
    const float4* __restrict__ x, ushort4* __restrict__ xb)
{
    int i = blockIdx.x * 256 + threadIdx.x;      // grid covers exactly 1.6M
    float4 v = x[i];
    ushort4 o;
    o.x = f2bf(v.x); o.y = f2bf(v.y); o.z = f2bf(v.z); o.w = f2bf(v.w);
    xb[i] = o;
}

// ---------------------------------------------------------------------------
// W -> bf16 in MFMA B-fragment order.
// frag f = ((s*4+kb)*8+nt); Wf[(f*64+lane)*8+j] = W[s][kb*32+(lane>>4)*8+j][nt*16+(lane&15)]
// ---------------------------------------------------------------------------
__global__ __launch_bounds__(256) void w_to_frags(
    const float* __restrict__ W, unsigned short* __restrict__ Wf)
{
    int gid = blockIdx.x * 256 + threadIdx.x;    // < 49152 exactly
    int j    = gid & 7;
    int lane = (gid >> 3) & 63;
    int rest = gid >> 9;
    int nt = rest & 7, kb = (rest >> 3) & 3, s = rest >> 5;
    int k = kb * 32 + ((lane >> 4) * 8) + j;
    int n = nt * 16 + (lane & 15);
    Wf[gid] = f2bf(W[((size_t)s * D + k) * D + n]);
}

// ---------------------------------------------------------------------------
// CSR build: histogram -> 3-kernel scan -> scatter (unchanged from R2).
// ---------------------------------------------------------------------------
__global__ __launch_bounds__(256) void edge_histogram(
    const int* __restrict__ rows, int* __restrict__ counts)
{
    int i = blockIdx.x * 256 + threadIdx.x;
    int s = blockIdx.x / 2500;
    atomicAdd(&counts[s * N_NODES + rows[i]], 1);
}

__global__ __launch_bounds__(256) void scan_partials(
    const int* __restrict__ counts, int* __restrict__ bsums)
{
    __shared__ int sm[256];
    int tid = threadIdx.x;
    int i = blockIdx.x * 256 + tid;
    sm[tid] = (i < NTOT) ? counts[i] : 0;
    __syncthreads();
    for (int off = 128; off > 0; off >>= 1) {
        if (tid < off) sm[tid] += sm[tid + off];
        __syncthreads();
    }
    if (tid == 0) bsums[blockIdx.x] = sm[0];
}

__global__ __launch_bounds__(1024) void scan_bsums(int* __restrict__ bsums)
{
    __shared__ int sm[1024];
    int tid = threadIdx.x;
    int v = (tid < NB_SCAN) ? bsums[tid] : 0;
    sm[tid] = v;
    __syncthreads();
    for (int off = 1; off < 1024; off <<= 1) {
        int t = (tid >= off) ? sm[tid - off] : 0;
        __syncthreads();
        sm[tid] += t;
        __syncthreads();
    }
    if (tid < NB_SCAN) bsums[tid] = sm[tid] - v;
}

__global__ __launch_bounds__(256) void scan_final(
    const int* __restrict__ counts, const int* __restrict__ bsums,
    int* __restrict__ row_ptr, int* __restrict__ wptr)
{
    __shared__ int sm[256];
    int tid = threadIdx.x;
    int i = blockIdx.x * 256 + tid;
    int v = (i < NTOT) ? counts[i] : 0;
    sm[tid] = v;
    __syncthreads();
    for (int off = 1; off < 256; off <<= 1) {
        int t = (tid >= off) ? sm[tid - off] : 0;
        __syncthreads();
        sm[tid] += t;
        __syncthreads();
    }
    int excl = sm[tid] - v + bsums[blockIdx.x];
    if (i < NTOT) { row_ptr[i] = excl; wptr[i] = excl; }
}

__global__ __launch_bounds__(256) void edge_scatter(
    const int* __restrict__ rows, const int* __restrict__ cols,
    const float* __restrict__ vals, int* __restrict__ wptr,
    float2* __restrict__ sorted)
{
    int i = blockIdx.x * 256 + threadIdx.x;
    int s = blockIdx.x / 2500;
    int pos = atomicAdd(&wptr[s * N_NODES + rows[i]], 1);
    sorted[pos] = make_float2(__int_as_float(cols[i]), vals[i]);
}

// ---------------------------------------------------------------------------
// Gather-SpMM from bf16 x: one wave per (support,row); per edge the wave
// reads 256B of xb (uint = 2 bf16 per lane), broadcast (col,val) by shfl.
// Output Y in bf16 (GEMM A-operand layout = plain row-major).
// ---------------------------------------------------------------------------
__global__ __launch_bounds__(256) void spmm_gather(
    const unsigned short* __restrict__ xb, const int* __restrict__ row_ptr,
    const int* __restrict__ row_end, const float2* __restrict__ sorted,
    unsigned short* __restrict__ Yb, int nrows)
{
    int wid  = (blockIdx.x * 256 + threadIdx.x) >> 6;
    int lane = threadIdx.x & 63;
    if (wid >= nrows) return;
    int start = row_ptr[wid];
    int end   = row_end[wid];
    float acc0 = 0.f, acc1 = 0.f;
    for (int j = start; j < end; j += 64) {
        int m = end - j; if (m > 64) m = 64;
        float2 ev = make_float2(0.f, 0.f);
        if (lane < m) ev = sorted[j + lane];
        for (int t = 0; t < m; ++t) {
            int   col = __float_as_int(__shfl(ev.x, t));
            float v   = __shfl(ev.y, t);
            unsigned int xv = ((const unsigned int*)(xb + (size_t)col * D))[lane];
            acc0 += v * __uint_as_float(xv << 16);
            acc1 += v * __uint_as_float(xv & 0xFFFF0000u);
        }
    }
    unsigned int o = (unsigned int)f2bf(acc0) | ((unsigned int)f2bf(acc1) << 16);
    ((unsigned int*)(Yb + (size_t)wid * D))[lane] = o;
}

// ---------------------------------------------------------------------------
// MFMA GEMM: out = relu(bias + sum_s Y_s @ W_s). One wave -> 16 rows x 128
// cols; 3 sup x 4 kb x 8 nt = 96 mfma_f32_16x16x32_bf16. A straight from
// bf16 Y (16B/lane), B from pre-packed Wf (L2-hot). No LDS, no barriers.
// A layout: A[m=lane&15][k=quad*8+j]; C/D: col=lane&15, row=quad*4+reg.
// ---------------------------------------------------------------------------
__global__ __launch_bounds__(256) void gemm_mfma(
    const unsigned short* __restrict__ Yb,   // [3*N_NODES][D] bf16
    const unsigned short* __restrict__ Wf,   // fragment-packed
    const float* __restrict__ bias,
    float* __restrict__ out)
{
    int wid  = blockIdx.x * 4 + (threadIdx.x >> 6);
    int lane = threadIdx.x & 63;
    if (wid >= NWAVES) return;
    const int m0   = wid * 16;
    const int quad = lane >> 4;
    const int l16  = lane & 15;

    f32x4 acc[8];
    #pragma unroll
    for (int nt = 0; nt < 8; ++nt) acc[nt] = (f32x4){0.f, 0.f, 0.f, 0.f};

    #pragma unroll
    for (int s = 0; s < N_SUP; ++s) {
        const unsigned short* ys = Yb + (size_t)s * N_NODES * D;
        #pragma unroll
        for (int kb = 0; kb < 4; ++kb) {
            s16x8 a = *(const s16x8*)(ys + (size_t)(m0 + l16) * D + kb * 32 + quad * 8);
            const unsigned short* wf = Wf + (size_t)((s * 4 + kb) * 8) * 64 * 8 + lane * 8;
            #pragma unroll
            for (int nt = 0; nt < 8; ++nt) {
                s16x8 b = *(const s16x8*)(wf + (size_t)nt * 64 * 8);
                acc[nt] = __builtin_amdgcn_mfma_f32_16x16x32_bf16(a, b, acc[nt], 0, 0, 0);
            }
        }
    }

    #pragma unroll
    for (int nt = 0; nt < 8; ++nt) {
        int col = nt * 16 + l16;
        float bv = bias[col];
        #pragma unroll
        for (int r = 0; r < 4; ++r) {
            int row = m0 + quad * 4 + r;
            out[(size_t)row * D + col] = fmaxf(acc[nt][r] + bv, 0.f);
        }
    }
}

extern "C" void kernel_launch(void* const* d_in, const int* in_sizes, int n_in,
                              void* d_out, int out_size, void* d_ws, size_t ws_size,
                              hipStream_t stream)
{
    const float* x         = (const float*)d_in[0];
    const int*   edge_rows = (const int*)  d_in[1];
    const int*   edge_cols = (const int*)  d_in[2];
    const float* edge_vals = (const float*)d_in[3];
    const float* weights   = (const float*)d_in[4];
    const float* bias      = (const float*)d_in[5];
    float* out = (float*)d_out;

    // workspace layout (256B aligned), total ~68.6 MB
    char* ws = (char*)d_ws;
    size_t off = 0;
    auto alloc = [&](size_t bytes) -> char* {
        char* p = ws + off;
        off += (bytes + 255) & ~(size_t)255;
        return p;
    };
    int*            counts  = (int*)            alloc((size_t)NTOT * 4);
    int*            row_ptr = (int*)            alloc((size_t)NTOT * 4);
    int*            wptr    = (int*)            alloc((size_t)NTOT * 4);
    int*            bsums   = (int*)            alloc(1024 * 4);
    float2*         sorted  = (float2*)         alloc((size_t)E_TOT * 8);
    unsigned short* xb      = (unsigned short*) alloc((size_t)N_NODES * D * 2);
    unsigned short* Wf      = (unsigned short*) alloc((size_t)N_SUP * D * D * 2);
    unsigned short* Yb      = (unsigned short*) alloc((size_t)NTOT * D * 2);

    // input converts (independent of CSR build)
    x_to_bf16 <<<(N_NODES * D / 4) / 256, 256, 0, stream>>>((const float4*)x, (ushort4*)xb);
    w_to_frags<<<(N_SUP * D * D) / 256, 256, 0, stream>>>(weights, Wf);

    // build CSR (all 3 supports at once)
    hipMemsetAsync(counts, 0, (size_t)NTOT * 4, stream);
    edge_histogram<<<E_TOT / 256, 256, 0, stream>>>(edge_rows, counts);
    scan_partials <<<NB_SCAN, 256, 0, stream>>>(counts, bsums);
    scan_bsums    <<<1, 1024, 0, stream>>>(bsums);
    scan_final    <<<NB_SCAN, 256, 0, stream>>>(counts, bsums, row_ptr, wptr);
    edge_scatter  <<<E_TOT / 256, 256, 0, stream>>>(edge_rows, edge_cols,
                                                    edge_vals, wptr, sorted);

    // gather all 150k rows, then one fused MFMA GEMM over 3 supports
    spmm_gather<<<NTOT / 4, 256, 0, stream>>>(xb, row_ptr, wptr, sorted, Yb, NTOT);
    gemm_mfma  <<<(NWAVES + 3) / 4, 256, 0, stream>>>(Yb, Wf, bias, out);
}